// Round 1
// baseline (106.405 us; speedup 1.0000x reference)
//
#include <hip/hip_runtime.h>

#define NCLUST 16

// t = clip(x * 64, -128, 127); nearest center (first-index tie-break, exact
// f32 |t-c| comparisons to match jnp.argmin bit-for-bit); out = c * 2/128.
__global__ __launch_bounds__(256) void lut_fakequant_kernel(
    const float* __restrict__ x,
    const float* __restrict__ centers,
    float* __restrict__ out,
    int n4, int tail, long long tail_base)
{
    // Centers are uniform across the grid -> compiler keeps them in SGPRs.
    float c[NCLUST];
#pragma unroll
    for (int k = 0; k < NCLUST; ++k) c[k] = centers[k];

    const int i = blockIdx.x * blockDim.x + threadIdx.x;

    if (i < n4) {
        const float4* __restrict__ x4 = (const float4*)x;
        float4* __restrict__ o4 = (float4*)out;
        float4 v = x4[i];
        float in[4] = {v.x, v.y, v.z, v.w};
        float res[4];
#pragma unroll
        for (int e = 0; e < 4; ++e) {
            float t = in[e] * 64.0f;                       // x/(2+1e-8)*128 == x*64 exactly in f32
            t = fminf(fmaxf(t, -128.0f), 127.0f);
            float best  = c[0];
            float bestd = __builtin_fabsf(t - c[0]);
#pragma unroll
            for (int k = 1; k < NCLUST; ++k) {
                float d = __builtin_fabsf(t - c[k]);
                bool lt = d < bestd;                       // strict: keep first index on tie
                best  = lt ? c[k] : best;
                bestd = fminf(d, bestd);
            }
            res[e] = best * 0.015625f;                     // c / 128 * 2, exact
        }
        o4[i] = make_float4(res[0], res[1], res[2], res[3]);
    }

    // Scalar tail (n % 4 != 0) — handled by the first `tail` threads of the grid.
    if (i < tail) {
        float t = x[tail_base + i] * 64.0f;
        t = fminf(fmaxf(t, -128.0f), 127.0f);
        float best  = c[0];
        float bestd = __builtin_fabsf(t - c[0]);
#pragma unroll
        for (int k = 1; k < NCLUST; ++k) {
            float d = __builtin_fabsf(t - c[k]);
            bool lt = d < bestd;
            best  = lt ? c[k] : best;
            bestd = fminf(d, bestd);
        }
        out[tail_base + i] = best * 0.015625f;
    }
}

extern "C" void kernel_launch(void* const* d_in, const int* in_sizes, int n_in,
                              void* d_out, int out_size, void* d_ws, size_t ws_size,
                              hipStream_t stream) {
    const float* x       = (const float*)d_in[0];
    const float* centers = (const float*)d_in[1];
    float* out           = (float*)d_out;

    const int n    = in_sizes[0];          // 12,845,056
    const int n4   = n / 4;                // 3,211,264 float4 groups
    const int tail = n - n4 * 4;           // 0 for this shape
    const long long tail_base = (long long)n4 * 4;

    const int block = 256;
    const int grid  = (n4 + block - 1) / block;   // 12,544 blocks

    lut_fakequant_kernel<<<grid, block, 0, stream>>>(x, centers, out, n4, tail, tail_base);
}

// Round 2
// 102.211 us; speedup vs baseline: 1.0410x; 1.0410x over previous
//
#include <hip/hip_runtime.h>

#define NCLUST 16
#define TBL 512          // buckets for s = 2t+256, s in [0,510]
#define EPT 8            // elements per thread (2 x float4)

// ---------------------------------------------------------------------------
// Setup: bucket b (t-interval [b/2-128, b/2-127.5]) -> bracketing center pair
// (c_j, c_{j+1}).  j = clamp(#{k : 2*c_k+256 <= b} - 1, 0, 14).  All predicates
// are exact in f32 (integers <= 512).
// ---------------------------------------------------------------------------
__global__ __launch_bounds__(512) void build_table_kernel(
    const float* __restrict__ centers, float2* __restrict__ tbl)
{
    int b = threadIdx.x;                 // 0..511
    float c[NCLUST];
#pragma unroll
    for (int k = 0; k < NCLUST; ++k) c[k] = centers[k];
    int cnt = 0;
#pragma unroll
    for (int k = 0; k < NCLUST; ++k)
        cnt += (fmaf(c[k], 2.0f, 256.0f) <= (float)b) ? 1 : 0;
    int j = cnt - 1;
    j = j < 0 ? 0 : (j > NCLUST - 2 ? NCLUST - 2 : j);
    tbl[b] = make_float2(c[j], c[j + 1]);
}

// ---------------------------------------------------------------------------
// Per-element: t = clip(x*64, -128, 127); bucket lookup; exact adjacent-pair
// compare (<= keeps the earlier index, matching jnp.argmin tie-break on the
// computed f32 distances); out = c * 2/128.
// ---------------------------------------------------------------------------
__device__ __forceinline__ float quant1(float xv, const float2* __restrict__ lut)
{
    float t = xv * 64.0f;                          // x/(2+1e-8)*128 == x*64 exactly
    t = fminf(fmaxf(t, -128.0f), 127.0f);
    float s = fmaf(t, 2.0f, 256.0f);               // [0, 510], shift < 2^-15
    int b = (int)s;                                // trunc == floor (s >= 0)
    float2 p = lut[b];
    float d0 = __builtin_fabsf(t - p.x);
    float d1 = __builtin_fabsf(t - p.y);
    return (d0 <= d1 ? p.x : p.y) * 0.015625f;     // c / 128 * 2, exact
}

__global__ __launch_bounds__(256) void lut_fakequant_kernel(
    const float* __restrict__ x,
    const float2* __restrict__ tbl,
    float* __restrict__ out,
    int n4, int tail)
{
    __shared__ __align__(16) float2 lut[TBL];
    // Stage 4 KB table into LDS: 256 threads x one float4 (two float2 entries).
    ((float4*)lut)[threadIdx.x] = ((const float4*)tbl)[threadIdx.x];
    __syncthreads();

    const float4* __restrict__ x4 = (const float4*)x;
    float4* __restrict__ o4 = (float4*)out;

    const int i0 = blockIdx.x * (256 * EPT / 4) + threadIdx.x;   // 2 float4/thread
    const int i1 = i0 + 256;
    const bool g0 = i0 < n4;
    const bool g1 = i1 < n4;

    float4 v0, v1;
    if (g0) v0 = x4[i0];
    if (g1) v1 = x4[i1];

    if (g0) {
        float4 r;
        r.x = quant1(v0.x, lut); r.y = quant1(v0.y, lut);
        r.z = quant1(v0.z, lut); r.w = quant1(v0.w, lut);
        o4[i0] = r;
    }
    if (g1) {
        float4 r;
        r.x = quant1(v1.x, lut); r.y = quant1(v1.y, lut);
        r.z = quant1(v1.z, lut); r.w = quant1(v1.w, lut);
        o4[i1] = r;
    }

    // Scalar tail (n % 4 != 0): first `tail` threads of block 0.
    if (blockIdx.x == 0 && threadIdx.x < tail) {
        long long idx = (long long)n4 * 4 + threadIdx.x;
        out[idx] = quant1(x[idx], lut);
    }
}

extern "C" void kernel_launch(void* const* d_in, const int* in_sizes, int n_in,
                              void* d_out, int out_size, void* d_ws, size_t ws_size,
                              hipStream_t stream) {
    const float* x       = (const float*)d_in[0];
    const float* centers = (const float*)d_in[1];
    float* out           = (float*)d_out;
    float2* tbl          = (float2*)d_ws;          // 4 KB scratch

    const int n    = in_sizes[0];                  // 12,845,056
    const int n4   = n / 4;                        // 3,211,264
    const int tail = n - n4 * 4;                   // 0 for this shape

    build_table_kernel<<<1, TBL, 0, stream>>>(centers, tbl);

    const int f4_per_block = 256 * EPT / 4;        // 512 float4 per block
    const int grid = (n4 + f4_per_block - 1) / f4_per_block;   // 6272
    lut_fakequant_kernel<<<grid, 256, 0, stream>>>(x, tbl, out, n4, tail);
}

// Round 3
// 100.183 us; speedup vs baseline: 1.0621x; 1.0202x over previous
//
#include <hip/hip_runtime.h>

#define NCLUST 16
#define TBL 512          // buckets over s = 128*u + 256, s in [0,510]
#define F4PT 4           // float4 per thread -> 16 elements/thread

// Exact-scaling trick: u = clamp(x, -2, 1.984375) == clip(x*64,-128,127) * 2^-6
// exactly (all scales are powers of two). Comparing fl(|u - c*2^-6|) is the
// 2^-6-scaled image of fl(|t - c|): identical ordering AND identical rounding
// collapse, so selection + tie-break match jnp.argmin bit-for-bit. The LUT
// stores scaled centers, so the selected value is the final output.
__device__ __forceinline__ float quant1(float xv, const float2* __restrict__ lut)
{
    float u = fminf(fmaxf(xv, -2.0f), 1.984375f);
    float s = fmaf(u, 128.0f, 256.0f);         // == fl(2t+256), in [0,510]
    int b = (int)s;
    float2 p = lut[b];
    float d0 = __builtin_fabsf(u - p.x);
    float d1 = __builtin_fabsf(u - p.y);
    return d0 <= d1 ? p.x : p.y;               // <= keeps earlier index on tie
}

__global__ __launch_bounds__(256) void lut_fakequant_kernel(
    const float* __restrict__ x,
    const float* __restrict__ centers,
    float* __restrict__ out,
    int n4, int tail)
{
    __shared__ __align__(16) float2 lut[TBL];
    __shared__ float cent[NCLUST];

    const float4* __restrict__ x4 = (const float4*)x;
    float4* __restrict__ o4 = (float4*)out;

    // Issue all global loads first so the table build hides under them.
    const int base = blockIdx.x * (256 * F4PT) + threadIdx.x;
    float4 v[F4PT];
    bool gok[F4PT];
#pragma unroll
    for (int r = 0; r < F4PT; ++r) {
        int idx = base + 256 * r;
        gok[r] = idx < n4;
        if (gok[r]) v[r] = x4[idx];
    }

    // --- Per-block LUT build -------------------------------------------------
    // Scaled centers: exact (x * 2^-6).
    if (threadIdx.x < NCLUST) cent[threadIdx.x] = centers[threadIdx.x] * 0.015625f;
    // Uniform copies for the count predicates (compiler scalarizes to SGPRs).
    float g[NCLUST];
#pragma unroll
    for (int k = 0; k < NCLUST; ++k) g[k] = centers[k] * 0.015625f;
    __syncthreads();

#pragma unroll
    for (int r = 0; r < TBL / 256; ++r) {
        int b = threadIdx.x + 256 * r;
        // bucket start in u-domain: (b-256)/128, exact in f32
        float tb = (float)(b - 256) * 0.0078125f;
        int cnt = 0;
#pragma unroll
        for (int k = 0; k < NCLUST; ++k) cnt += (g[k] <= tb) ? 1 : 0;
        int j = cnt - 1;
        j = j < 0 ? 0 : (j > NCLUST - 2 ? NCLUST - 2 : j);
        // cent[j], cent[j+1]: same-j lanes broadcast; distinct j -> distinct
        // banks (j <= 15 < 32) -> conflict-free.
        lut[b] = make_float2(cent[j], cent[j + 1]);
    }
    __syncthreads();
    // ------------------------------------------------------------------------

#pragma unroll
    for (int r = 0; r < F4PT; ++r) {
        if (gok[r]) {
            float4 res;
            res.x = quant1(v[r].x, lut);
            res.y = quant1(v[r].y, lut);
            res.z = quant1(v[r].z, lut);
            res.w = quant1(v[r].w, lut);
            o4[base + 256 * r] = res;
        }
    }

    // Scalar tail (n % 4 != 0): first `tail` threads of block 0.
    if (blockIdx.x == 0 && threadIdx.x < tail) {
        long long idx = (long long)n4 * 4 + threadIdx.x;
        out[idx] = quant1(x[idx], lut);
    }
}

extern "C" void kernel_launch(void* const* d_in, const int* in_sizes, int n_in,
                              void* d_out, int out_size, void* d_ws, size_t ws_size,
                              hipStream_t stream) {
    const float* x       = (const float*)d_in[0];
    const float* centers = (const float*)d_in[1];
    float* out           = (float*)d_out;

    const int n    = in_sizes[0];                 // 12,845,056
    const int n4   = n / 4;                       // 3,211,264
    const int tail = n - n4 * 4;                  // 0 for this shape

    const int f4_per_block = 256 * F4PT;          // 1024 float4 per block
    const int grid = (n4 + f4_per_block - 1) / f4_per_block;   // 3136
    lut_fakequant_kernel<<<grid, 256, 0, stream>>>(x, centers, out, n4, tail);
}